// Round 11
// baseline (45.248 us; speedup 1.0000x reference)
//
#include <hip/hip_runtime.h>
#include <math.h>

// Health_State_Analysis: B=16384 rows, S=2560 fp32 -> 15 stats/row.
// R5 body (best: 36.7us) made PERSISTENT: 2048 blocks x 4 row-pair iterations,
// next iteration's loads issued right AFTER the barrier (prefetch hides HBM
// latency under boundary math + pass-2 + tail; continuous per-slot load stream).
// k1: 2 waves/row, coalesced interleave, DPP reductions, packed moments,
//     lag-correlation (r1,r2), launch_bounds(256,6). k2: f64 finalization.

typedef float f32x2 __attribute__((ext_vector_type(2)));
typedef float f32x4 __attribute__((ext_vector_type(4)));

constexpr int S_LEN = 2560;
constexpr int NROWS = 16384;

#define DPP_ADD_F32(x, ctrl) do { \
    int t_ = __builtin_amdgcn_update_dpp(0, __float_as_int(x), ctrl, 0xf, 0xf, false); \
    x += __int_as_float(t_); } while (0)
#define DPP_MAX_F32(x, ctrl) do { \
    int t_ = __builtin_amdgcn_update_dpp(__float_as_int(x), __float_as_int(x), ctrl, 0xf, 0xf, false); \
    x = fmaxf(x, __int_as_float(t_)); } while (0)
#define DPP_MIN_F32(x, ctrl) do { \
    int t_ = __builtin_amdgcn_update_dpp(__float_as_int(x), __float_as_int(x), ctrl, 0xf, 0xf, false); \
    x = fminf(x, __int_as_float(t_)); } while (0)

__device__ __forceinline__ float wave_sum_f32(float x) {
    DPP_ADD_F32(x, 0x111); DPP_ADD_F32(x, 0x112); DPP_ADD_F32(x, 0x114);
    DPP_ADD_F32(x, 0x118); DPP_ADD_F32(x, 0x142); DPP_ADD_F32(x, 0x143);
    return x;  // total in lane 63
}
__device__ __forceinline__ float wave_max_f32(float x) {
    DPP_MAX_F32(x, 0x111); DPP_MAX_F32(x, 0x112); DPP_MAX_F32(x, 0x114);
    DPP_MAX_F32(x, 0x118); DPP_MAX_F32(x, 0x142); DPP_MAX_F32(x, 0x143);
    return x;
}
__device__ __forceinline__ float wave_min_f32(float x) {
    DPP_MIN_F32(x, 0x111); DPP_MIN_F32(x, 0x112); DPP_MIN_F32(x, 0x114);
    DPP_MIN_F32(x, 0x118); DPP_MIN_F32(x, 0x142); DPP_MIN_F32(x, 0x143);
    return x;
}
__device__ __forceinline__ double wave_sum_f64(double x) {
#define DPP_ADD_F64(ctrl) do { \
    long long b_ = __double_as_longlong(x); \
    int lo_ = __builtin_amdgcn_update_dpp(0, (int)(b_ & 0xffffffffLL), ctrl, 0xf, 0xf, false); \
    int hi_ = __builtin_amdgcn_update_dpp(0, (int)(b_ >> 32), ctrl, 0xf, 0xf, false); \
    x += __longlong_as_double(((long long)hi_ << 32) | (unsigned int)lo_); } while (0)
    DPP_ADD_F64(0x111); DPP_ADD_F64(0x112); DPP_ADD_F64(0x114);
    DPP_ADD_F64(0x118); DPP_ADD_F64(0x142); DPP_ADD_F64(0x143);
#undef DPP_ADD_F64
    return x;  // total in lane 63
}
__device__ __forceinline__ double readlane_f64(double x, int l) {
    long long b = __double_as_longlong(x);
    int lo = __builtin_amdgcn_readlane((int)(b & 0xffffffffLL), l);
    int hi = __builtin_amdgcn_readlane((int)(b >> 32), l);
    return __longlong_as_double(((long long)hi << 32) | (unsigned int)lo);
}

__global__ __launch_bounds__(256, 6)
void health_pass1(const float* __restrict__ in, float* __restrict__ ws) {
    __shared__ double Lsum[2][4], Lsq[2][4];   // double-buffered by it&1
    __shared__ float  Lnb[2][2][2];

    const int lane = threadIdx.x & 63;
    const int wid  = threadIdx.x >> 6;   // 0..3
    const int hidx = wid & 1;            // half of row
    const int rsl  = wid >> 1;           // row slot in block
    const int nli  = (lane + 1) & 63;

    // iteration 0 loads
    {
        const int row0 = blockIdx.x * 8 + rsl;
        const f32x4* rp = reinterpret_cast<const f32x4*>(in)
                        + (size_t)row0 * (S_LEN / 4) + hidx * (1280 / 4) + lane;
#pragma unroll
        for (int k = 0; k < 5; ++k) {
            // declared below; loaded into X via first-iteration init
        }
    }

    f32x4 X[5];
    {
        const int row0 = blockIdx.x * 8 + rsl;
        const f32x4* rp = reinterpret_cast<const f32x4*>(in)
                        + (size_t)row0 * (S_LEN / 4) + hidx * (1280 / 4) + lane;
#pragma unroll
        for (int k = 0; k < 5; ++k) X[k] = rp[k * 64];
    }

#pragma unroll
    for (int it = 0; it < 4; ++it) {
        const int s   = it & 1;
        const int row = blockIdx.x * 8 + it * 2 + rsl;

        // ---- pass 1: packed raw sums on X ----
        f32x2 sp = {0.f, 0.f}, qp = {0.f, 0.f}, sabsp = {0.f, 0.f};
        f32x2 vmaxp = {-INFINITY, -INFINITY}, vminp = {INFINITY, INFINITY};
#pragma unroll
        for (int k = 0; k < 5; ++k) {
            f32x2 lo = __builtin_shufflevector(X[k], X[k], 0, 1);
            f32x2 hi = __builtin_shufflevector(X[k], X[k], 2, 3);
            sp += lo + hi;
            qp = __builtin_elementwise_fma(lo, lo, qp);
            qp = __builtin_elementwise_fma(hi, hi, qp);
            sabsp += __builtin_elementwise_max(lo, -lo);
            sabsp += __builtin_elementwise_max(hi, -hi);
            vmaxp = __builtin_elementwise_max(vmaxp, __builtin_elementwise_max(lo, hi));
            vminp = __builtin_elementwise_min(vminp, __builtin_elementwise_min(lo, hi));
        }

        const double sum_l = (double)sp.x + (double)sp.y;
        const double sq_l  = (double)qp.x + (double)qp.y;
        const double sum_u = readlane_f64(wave_sum_f64(sum_l), 63);
        const double sq_u  = readlane_f64(wave_sum_f64(sq_l), 63);

        const float sabs_t = wave_sum_f32(sabsp.x + sabsp.y);
        const float vmax_t = wave_max_f32(fmaxf(vmaxp.x, vmaxp.y));
        const float vmin_t = wave_min_f32(fminf(vminp.x, vminp.y));

        // exchange sums with partner wave (other half of row)
        if (lane == 0) {
            Lsum[s][wid] = sum_u;  Lsq[s][wid] = sq_u;
            if (hidx == 1) { Lnb[s][rsl][0] = X[0][0]; Lnb[s][rsl][1] = X[0][1]; }
        }
        __syncthreads();

        // ---- prefetch next iteration's tiles (post-barrier: no vmcnt drain) ----
        f32x4 Xn[5];
        if (it < 3) {
            const f32x4* rpn = reinterpret_cast<const f32x4*>(in)
                             + (size_t)(row + 2) * (S_LEN / 4) + hidx * (1280 / 4) + lane;
#pragma unroll
            for (int k = 0; k < 5; ++k) Xn[k] = rpn[k * 64];
        }

        const double tsum = Lsum[s][rsl * 2] + Lsum[s][rsl * 2 + 1];
        const double tsq  = Lsq[s][rsl * 2]  + Lsq[s][rsl * 2 + 1];

        const double mean = tsum * (1.0 / S_LEN);
        const double var  = (tsq - tsum * mean) * (1.0 / (S_LEN - 1));  // n*mean^2 ~1 << tsq
        const double thr  = 3.0 * sqrt(var);
        const double bhi = mean + thr, blo = mean - thr;
        float bhi_f = (float)bhi;
        if ((double)bhi_f > bhi) bhi_f = __int_as_float(__float_as_int(bhi_f) - 1);  // RD (bhi>0)
        float blo_f = (float)blo;
        if ((double)blo_f < blo) blo_f = __int_as_float(__float_as_int(blo_f) - 1);  // RU (blo<0)

        // half0 tail splices x[1280],x[1281]; half1 tail pairs don't exist -> 0
        const float nbv0 = (hidx == 0) ? Lnb[s][rsl][0] : 0.f;
        const float nbv1 = (hidx == 0) ? Lnb[s][rsl][1] : 0.f;
        const float mf = (float)mean;
        const f32x2 nmf2 = {-mf, -mf};
        const unsigned long long tail_ok = (hidx == 0) ? ~0ULL : 0x7FFFFFFFFFFFFFFFULL;

        // ---- pass 2: moments (packed), outliers, zcr, lag correlations ----
        f32x2 c3p = {0.f, 0.f}, c4p = {0.f, 0.f};
        float r1 = 0.f, r2 = 0.f;
        int outc = 0, zcc = 0;

#pragma unroll
        for (int k = 0; k < 5; ++k) {
            const float x0 = X[k][0], x1 = X[k][1], x2v = X[k][2], x3 = X[k][3];
            const int kn = (k == 4) ? 0 : (k + 1);
            float v0 = (lane == 0) ? X[kn][0] : x0;
            float v1 = (lane == 0) ? X[kn][1] : x1;
            float n0 = __shfl(v0, nli);
            float n1 = __shfl(v1, nli);
            if (k == 4 && lane == 63) { n0 = nbv0; n1 = nbv1; }

            f32x2 lo = __builtin_shufflevector(X[k], X[k], 0, 1);
            f32x2 hi = __builtin_shufflevector(X[k], X[k], 2, 3);
            f32x2 cl = lo + nmf2, ch = hi + nmf2;
            f32x2 ql = cl * cl,  qh = ch * ch;
            c3p = __builtin_elementwise_fma(ql, cl, c3p);
            c3p = __builtin_elementwise_fma(qh, ch, c3p);
            c4p = __builtin_elementwise_fma(ql, ql, c4p);
            c4p = __builtin_elementwise_fma(qh, qh, c4p);

            outc += __popcll(__ballot(x0  > bhi_f || x0  < blo_f));
            outc += __popcll(__ballot(x1  > bhi_f || x1  < blo_f));
            outc += __popcll(__ballot(x2v > bhi_f || x2v < blo_f));
            outc += __popcll(__ballot(x3  > bhi_f || x3  < blo_f));

            const unsigned long long m0 = __ballot(x0  < 0.f);
            const unsigned long long m1 = __ballot(x1  < 0.f);
            const unsigned long long m2 = __ballot(x2v < 0.f);
            const unsigned long long m3 = __ballot(x3  < 0.f);
            const unsigned long long mn = __ballot(n0  < 0.f);
            zcc += __popcll(m0 ^ m1) + __popcll(m1 ^ m2) + __popcll(m2 ^ m3);
            zcc += __popcll((m3 ^ mn) & ((k == 4) ? tail_ok : ~0ULL));

            r1 = fmaf(x0, x1, fmaf(x1, x2v, fmaf(x2v, x3, fmaf(x3, n0, r1))));
            r2 = fmaf(x0, x2v, fmaf(x1, x3, fmaf(x2v, n0, fmaf(x3, n1, r2))));
        }

        const float c3_t = wave_sum_f32(c3p.x + c3p.y);
        const float c4_t = wave_sum_f32(c4p.x + c4p.y);
        const float r1_t = wave_sum_f32(r1);
        const float r2_t = wave_sum_f32(r2);

        float ep_a, ep_b;   // half0: x[0],x[1];  half1: x[2558],x[2559]
        if (hidx == 0) {
            ep_a = __int_as_float(__builtin_amdgcn_readlane(__float_as_int(X[0][0]), 0));
            ep_b = __int_as_float(__builtin_amdgcn_readlane(__float_as_int(X[0][1]), 0));
        } else {
            ep_a = X[4][2];  ep_b = X[4][3];   // valid on lane 63 (the storing lane)
        }

        if (lane == 63) {
            double2* Wd = reinterpret_cast<double2*>(ws);
            f32x4*   Wf = reinterpret_cast<f32x4*>(ws);
            double2 dsum; dsum.x = sum_u; dsum.y = sq_u;
            Wd[(size_t)hidx * NROWS + row] = dsum;                       // chunks 0,1
            const size_t b = (size_t)(2 + hidx * 3) * NROWS + row;       // chunks 2..7
            Wf[b]             = f32x4{sabs_t, vmax_t, vmin_t, c3_t};
            Wf[b + NROWS]     = f32x4{c4_t, r1_t, r2_t, (float)outc};
            Wf[b + 2 * NROWS] = f32x4{(float)zcc, ep_a, ep_b, 0.f};
        }

        // rotate prefetch buffer in
        if (it < 3) {
#pragma unroll
            for (int k = 0; k < 5; ++k) X[k] = Xn[k];
        }
    }
}

__global__ __launch_bounds__(256)
void health_finalize(const float* __restrict__ ws, float* __restrict__ out) {
    const int row = blockIdx.x * 256 + threadIdx.x;
    const double2* Wd = reinterpret_cast<const double2*>(ws);
    const f32x4*   Wf = reinterpret_cast<const f32x4*>(ws);

    const double2 s0 = Wd[row], s1 = Wd[NROWS + row];
    const f32x4 a0 = Wf[2 * NROWS + row], a1 = Wf[3 * NROWS + row], a2 = Wf[4 * NROWS + row];
    const f32x4 b0 = Wf[5 * NROWS + row], b1 = Wf[6 * NROWS + row], b2 = Wf[7 * NROWS + row];

    const double tsum = s0.x + s1.x;
    const double tsq  = s0.y + s1.y;
    const double mean = tsum * (1.0 / S_LEN);
    const double var  = (tsq - tsum * mean) * (1.0 / (S_LEN - 1));
    const double stdv = sqrt(var);

    const float tabs = a0[0] + b0[0];
    const float tmax = fmaxf(a0[1], b0[1]);
    const float tmin = fminf(a0[2], b0[2]);
    const float c3t  = a0[3] + b0[3];
    const float c4t  = a1[0] + b1[0];
    const double r1t = (double)a1[1] + (double)b1[1];
    const double r2t = (double)a1[2] + (double)b1[2];
    const float outt = a1[3] + b1[3];
    const float zct  = a2[0] + b2[0];
    const double e0 = (double)a2[1], e1 = (double)a2[2];   // x[0], x[1]
    const double e2 = (double)b2[1], e3 = (double)b2[2];   // x[2558], x[2559]

    const double rms  = sqrt(tsq * (1.0 / S_LEN));
    const double m3   = (double)c3t * (1.0 / S_LEN);
    const double m4   = (double)c4t * (1.0 / S_LEN);
    const double skew = m3 / (var * stdv);
    const double kurt = m4 / (var * var);
    const float  amax = fmaxf(fabsf(tmax), fabsf(tmin));
    const double shape   = rms * (double)S_LEN / (double)tabs;
    const double impulse = (double)amax * (double)S_LEN / (double)tabs;

    // Hjorth via lag-correlation identities (exact over the f32 samples):
    const double Q = tsq;
    const double s1q = 2.0 * Q - 2.0 * r1t - e0 * e0 - e3 * e3;
    const double s2q = 6.0 * Q - 8.0 * r1t + 2.0 * r2t
                     + 4.0 * (e0 * e1 + e2 * e3)
                     - 5.0 * e0 * e0 - e1 * e1 - e2 * e2 - 5.0 * e3 * e3;
    const double sd1 = e3 - e0;
    const double sd2 = (e3 - e2) - (e1 - e0);
    const double var1 = (s1q - sd1 * sd1 * (1.0 / (S_LEN - 1))) * (1.0 / (S_LEN - 2));
    const double var2 = (s2q - sd2 * sd2 * (1.0 / (S_LEN - 2))) * (1.0 / (S_LEN - 3));

    float* o = out + (size_t)row * 15;
    o[0]  = (float)mean;
    o[1]  = tmax;
    o[2]  = tmin;
    o[3]  = tmax - tmin;
    o[4]  = (float)var;
    o[5]  = (float)rms;
    o[6]  = (float)skew;
    o[7]  = (float)kurt;
    o[8]  = (float)shape;
    o[9]  = (float)impulse;
    o[10] = outt;
    o[11] = zct * (1.0f / (2.0f * S_LEN));
    o[12] = (float)var;
    o[13] = (float)sqrt(var1 / var);
    o[14] = (float)sqrt(var2 / var1);
}

extern "C" void kernel_launch(void* const* d_in, const int* in_sizes, int n_in,
                              void* d_out, int out_size, void* d_ws, size_t ws_size,
                              hipStream_t stream) {
    (void)in_sizes; (void)n_in; (void)ws_size; (void)out_size;
    const float* in = (const float*)d_in[0];
    float* out = (float*)d_out;
    float* ws  = (float*)d_ws;
    // persistent: 2048 blocks x 4 row-pair iterations = 16384 rows
    health_pass1<<<2048, 256, 0, stream>>>(in, ws);
    health_finalize<<<64, 256, 0, stream>>>(ws, out);
}

// Round 12
// 41.232 us; speedup vs baseline: 1.0974x; 1.0974x over previous
//
#include <hip/hip_runtime.h>
#include <math.h>

// Health_State_Analysis: B=16384 rows, S=2560 fp32 -> 15 stats/row.
// PROVEN OPTIMUM (R5, 36.7us): k1 2 waves/row, coalesced interleave, DPP
// reductions, packed moments, lag-correlation (r1,r2) replacing diff streams,
// launch_bounds(256,6). k2: 16384 threads, f64 finalization incl. Hjorth.
// Levers tested and REJECTED: 1-wave/row (-4.4us), fused epilogue (-6.6),
// 8-wave cap (-5.8, spill), pass rebalance (-2.2), nontemporal (-3.5),
// persistent+prefetch (-8.5, spill).

typedef float f32x2 __attribute__((ext_vector_type(2)));
typedef float f32x4 __attribute__((ext_vector_type(4)));

constexpr int S_LEN = 2560;
constexpr int NROWS = 16384;

#define DPP_ADD_F32(x, ctrl) do { \
    int t_ = __builtin_amdgcn_update_dpp(0, __float_as_int(x), ctrl, 0xf, 0xf, false); \
    x += __int_as_float(t_); } while (0)
#define DPP_MAX_F32(x, ctrl) do { \
    int t_ = __builtin_amdgcn_update_dpp(__float_as_int(x), __float_as_int(x), ctrl, 0xf, 0xf, false); \
    x = fmaxf(x, __int_as_float(t_)); } while (0)
#define DPP_MIN_F32(x, ctrl) do { \
    int t_ = __builtin_amdgcn_update_dpp(__float_as_int(x), __float_as_int(x), ctrl, 0xf, 0xf, false); \
    x = fminf(x, __int_as_float(t_)); } while (0)

__device__ __forceinline__ float wave_sum_f32(float x) {
    DPP_ADD_F32(x, 0x111); DPP_ADD_F32(x, 0x112); DPP_ADD_F32(x, 0x114);
    DPP_ADD_F32(x, 0x118); DPP_ADD_F32(x, 0x142); DPP_ADD_F32(x, 0x143);
    return x;  // total in lane 63
}
__device__ __forceinline__ float wave_max_f32(float x) {
    DPP_MAX_F32(x, 0x111); DPP_MAX_F32(x, 0x112); DPP_MAX_F32(x, 0x114);
    DPP_MAX_F32(x, 0x118); DPP_MAX_F32(x, 0x142); DPP_MAX_F32(x, 0x143);
    return x;
}
__device__ __forceinline__ float wave_min_f32(float x) {
    DPP_MIN_F32(x, 0x111); DPP_MIN_F32(x, 0x112); DPP_MIN_F32(x, 0x114);
    DPP_MIN_F32(x, 0x118); DPP_MIN_F32(x, 0x142); DPP_MIN_F32(x, 0x143);
    return x;
}
__device__ __forceinline__ double wave_sum_f64(double x) {
#define DPP_ADD_F64(ctrl) do { \
    long long b_ = __double_as_longlong(x); \
    int lo_ = __builtin_amdgcn_update_dpp(0, (int)(b_ & 0xffffffffLL), ctrl, 0xf, 0xf, false); \
    int hi_ = __builtin_amdgcn_update_dpp(0, (int)(b_ >> 32), ctrl, 0xf, 0xf, false); \
    x += __longlong_as_double(((long long)hi_ << 32) | (unsigned int)lo_); } while (0)
    DPP_ADD_F64(0x111); DPP_ADD_F64(0x112); DPP_ADD_F64(0x114);
    DPP_ADD_F64(0x118); DPP_ADD_F64(0x142); DPP_ADD_F64(0x143);
#undef DPP_ADD_F64
    return x;  // total in lane 63
}
__device__ __forceinline__ double readlane_f64(double x, int l) {
    long long b = __double_as_longlong(x);
    int lo = __builtin_amdgcn_readlane((int)(b & 0xffffffffLL), l);
    int hi = __builtin_amdgcn_readlane((int)(b >> 32), l);
    return __longlong_as_double(((long long)hi << 32) | (unsigned int)lo);
}

__global__ __launch_bounds__(256, 6)
void health_pass1(const float* __restrict__ in, float* __restrict__ ws) {
    __shared__ double Lsum[4], Lsq[4];
    __shared__ float  Lnb[2][2];

    const int lane = threadIdx.x & 63;
    const int wid  = threadIdx.x >> 6;   // 0..3
    const int hidx = wid & 1;            // half of row
    const int rsl  = wid >> 1;           // row slot in block
    const int row  = blockIdx.x * 2 + rsl;

    const f32x4* rp = reinterpret_cast<const f32x4*>(in)
                    + (size_t)row * (S_LEN / 4) + hidx * (1280 / 4) + lane;

    // ---- pass 1: coalesced load + raw sums (packed f32 -> f64 per lane) ----
    f32x4 X[5];
#pragma unroll
    for (int k = 0; k < 5; ++k) X[k] = rp[k * 64];

    f32x2 sp = {0.f, 0.f}, qp = {0.f, 0.f}, sabsp = {0.f, 0.f};
    f32x2 vmaxp = {-INFINITY, -INFINITY}, vminp = {INFINITY, INFINITY};
#pragma unroll
    for (int k = 0; k < 5; ++k) {
        f32x2 lo = __builtin_shufflevector(X[k], X[k], 0, 1);
        f32x2 hi = __builtin_shufflevector(X[k], X[k], 2, 3);
        sp += lo + hi;
        qp = __builtin_elementwise_fma(lo, lo, qp);
        qp = __builtin_elementwise_fma(hi, hi, qp);
        sabsp += __builtin_elementwise_max(lo, -lo);
        sabsp += __builtin_elementwise_max(hi, -hi);
        vmaxp = __builtin_elementwise_max(vmaxp, __builtin_elementwise_max(lo, hi));
        vminp = __builtin_elementwise_min(vminp, __builtin_elementwise_min(lo, hi));
    }

    const double sum_l = (double)sp.x + (double)sp.y;
    const double sq_l  = (double)qp.x + (double)qp.y;
    const double sum_u = readlane_f64(wave_sum_f64(sum_l), 63);
    const double sq_u  = readlane_f64(wave_sum_f64(sq_l), 63);

    float sabs = wave_sum_f32(sabsp.x + sabsp.y);
    float vmax = wave_max_f32(fmaxf(vmaxp.x, vmaxp.y));
    float vmin = wave_min_f32(fminf(vminp.x, vminp.y));

    // exchange sums with partner wave (other half of row)
    if (lane == 0) {
        Lsum[wid] = sum_u;  Lsq[wid] = sq_u;
        if (hidx == 1) { Lnb[rsl][0] = X[0][0]; Lnb[rsl][1] = X[0][1]; }
    }
    __syncthreads();
    const double tsum = Lsum[rsl * 2] + Lsum[rsl * 2 + 1];
    const double tsq  = Lsq[rsl * 2]  + Lsq[rsl * 2 + 1];

    const double mean = tsum * (1.0 / S_LEN);
    const double var  = (tsq - tsum * mean) * (1.0 / (S_LEN - 1));  // n*mean^2 ~1 << tsq
    const double thr  = 3.0 * sqrt(var);
    const double bhi = mean + thr, blo = mean - thr;
    float bhi_f = (float)bhi;
    if ((double)bhi_f > bhi) bhi_f = __int_as_float(__float_as_int(bhi_f) - 1);  // RD (bhi>0)
    float blo_f = (float)blo;
    if ((double)blo_f < blo) blo_f = __int_as_float(__float_as_int(blo_f) - 1);  // RU (blo<0)

    // half0 tail splices x[1280],x[1281]; half1 tail pairs don't exist -> 0
    // (zero neighbor makes the invalid lag products vanish exactly)
    const float nbv0 = (hidx == 0) ? Lnb[rsl][0] : 0.f;
    const float nbv1 = (hidx == 0) ? Lnb[rsl][1] : 0.f;
    const float mf = (float)mean;
    const f32x2 nmf2 = {-mf, -mf};
    const unsigned long long tail_ok = (hidx == 0) ? ~0ULL : 0x7FFFFFFFFFFFFFFFULL;

    // ---- pass 2: moments (packed), outliers, zcr, lag correlations ----
    f32x2 c3p = {0.f, 0.f}, c4p = {0.f, 0.f};
    float r1 = 0.f, r2 = 0.f;
    int outc = 0, zcc = 0;
    const int nli = (lane + 1) & 63;

#pragma unroll
    for (int k = 0; k < 5; ++k) {
        const float x0 = X[k][0], x1 = X[k][1], x2v = X[k][2], x3 = X[k][3];
        const int kn = (k == 4) ? 0 : (k + 1);
        float v0 = (lane == 0) ? X[kn][0] : x0;
        float v1 = (lane == 0) ? X[kn][1] : x1;
        float n0 = __shfl(v0, nli);
        float n1 = __shfl(v1, nli);
        if (k == 4 && lane == 63) { n0 = nbv0; n1 = nbv1; }

        f32x2 lo = __builtin_shufflevector(X[k], X[k], 0, 1);
        f32x2 hi = __builtin_shufflevector(X[k], X[k], 2, 3);
        f32x2 cl = lo + nmf2, ch = hi + nmf2;
        f32x2 ql = cl * cl,  qh = ch * ch;
        c3p = __builtin_elementwise_fma(ql, cl, c3p);
        c3p = __builtin_elementwise_fma(qh, ch, c3p);
        c4p = __builtin_elementwise_fma(ql, ql, c4p);
        c4p = __builtin_elementwise_fma(qh, qh, c4p);

        outc += __popcll(__ballot(x0  > bhi_f || x0  < blo_f));
        outc += __popcll(__ballot(x1  > bhi_f || x1  < blo_f));
        outc += __popcll(__ballot(x2v > bhi_f || x2v < blo_f));
        outc += __popcll(__ballot(x3  > bhi_f || x3  < blo_f));

        const unsigned long long m0 = __ballot(x0  < 0.f);
        const unsigned long long m1 = __ballot(x1  < 0.f);
        const unsigned long long m2 = __ballot(x2v < 0.f);
        const unsigned long long m3 = __ballot(x3  < 0.f);
        const unsigned long long mn = __ballot(n0  < 0.f);
        zcc += __popcll(m0 ^ m1) + __popcll(m1 ^ m2) + __popcll(m2 ^ m3);
        zcc += __popcll((m3 ^ mn) & ((k == 4) ? tail_ok : ~0ULL));

        // lag-1 / lag-2 correlations (replace d1/d2 squared-diff streams)
        r1 = fmaf(x0, x1, fmaf(x1, x2v, fmaf(x2v, x3, fmaf(x3, n0, r1))));
        r2 = fmaf(x0, x2v, fmaf(x1, x3, fmaf(x2v, n0, fmaf(x3, n1, r2))));
    }

    float sabs_t = sabs;
    float c3_t   = wave_sum_f32(c3p.x + c3p.y);
    float c4_t   = wave_sum_f32(c4p.x + c4p.y);
    float r1_t   = wave_sum_f32(r1);
    float r2_t   = wave_sum_f32(r2);
    float vmax_t = vmax;
    float vmin_t = vmin;

    float ep_a, ep_b;   // half0: x[0],x[1];  half1: x[2558],x[2559]
    if (hidx == 0) {
        ep_a = __int_as_float(__builtin_amdgcn_readlane(__float_as_int(X[0][0]), 0));
        ep_b = __int_as_float(__builtin_amdgcn_readlane(__float_as_int(X[0][1]), 0));
    } else {
        ep_a = X[4][2];  ep_b = X[4][3];   // valid on lane 63 (the storing lane)
    }

    if (lane == 63) {
        double2* Wd = reinterpret_cast<double2*>(ws);
        f32x4*   Wf = reinterpret_cast<f32x4*>(ws);
        double2 dsum; dsum.x = sum_u; dsum.y = sq_u;
        Wd[(size_t)hidx * NROWS + row] = dsum;                       // chunks 0,1
        const size_t b = (size_t)(2 + hidx * 3) * NROWS + row;       // chunks 2..7
        Wf[b]             = f32x4{sabs_t, vmax_t, vmin_t, c3_t};
        Wf[b + NROWS]     = f32x4{c4_t, r1_t, r2_t, (float)outc};
        Wf[b + 2 * NROWS] = f32x4{(float)zcc, ep_a, ep_b, 0.f};
    }
}

__global__ __launch_bounds__(256)
void health_finalize(const float* __restrict__ ws, float* __restrict__ out) {
    const int row = blockIdx.x * 256 + threadIdx.x;
    const double2* Wd = reinterpret_cast<const double2*>(ws);
    const f32x4*   Wf = reinterpret_cast<const f32x4*>(ws);

    const double2 s0 = Wd[row], s1 = Wd[NROWS + row];
    const f32x4 a0 = Wf[2 * NROWS + row], a1 = Wf[3 * NROWS + row], a2 = Wf[4 * NROWS + row];
    const f32x4 b0 = Wf[5 * NROWS + row], b1 = Wf[6 * NROWS + row], b2 = Wf[7 * NROWS + row];

    const double tsum = s0.x + s1.x;
    const double tsq  = s0.y + s1.y;
    const double mean = tsum * (1.0 / S_LEN);
    const double var  = (tsq - tsum * mean) * (1.0 / (S_LEN - 1));
    const double stdv = sqrt(var);

    const float tabs = a0[0] + b0[0];
    const float tmax = fmaxf(a0[1], b0[1]);
    const float tmin = fminf(a0[2], b0[2]);
    const float c3t  = a0[3] + b0[3];
    const float c4t  = a1[0] + b1[0];
    const double r1t = (double)a1[1] + (double)b1[1];
    const double r2t = (double)a1[2] + (double)b1[2];
    const float outt = a1[3] + b1[3];
    const float zct  = a2[0] + b2[0];
    const double e0 = (double)a2[1], e1 = (double)a2[2];   // x[0], x[1]
    const double e2 = (double)b2[1], e3 = (double)b2[2];   // x[2558], x[2559]

    const double rms  = sqrt(tsq * (1.0 / S_LEN));
    const double m3   = (double)c3t * (1.0 / S_LEN);
    const double m4   = (double)c4t * (1.0 / S_LEN);
    const double skew = m3 / (var * stdv);
    const double kurt = m4 / (var * var);
    const float  amax = fmaxf(fabsf(tmax), fabsf(tmin));
    const double shape   = rms * (double)S_LEN / (double)tabs;
    const double impulse = (double)amax * (double)S_LEN / (double)tabs;

    // Hjorth via lag-correlation identities (exact over the f32 samples):
    const double Q = tsq;
    const double s1q = 2.0 * Q - 2.0 * r1t - e0 * e0 - e3 * e3;
    const double s2q = 6.0 * Q - 8.0 * r1t + 2.0 * r2t
                     + 4.0 * (e0 * e1 + e2 * e3)
                     - 5.0 * e0 * e0 - e1 * e1 - e2 * e2 - 5.0 * e3 * e3;
    const double sd1 = e3 - e0;
    const double sd2 = (e3 - e2) - (e1 - e0);
    const double var1 = (s1q - sd1 * sd1 * (1.0 / (S_LEN - 1))) * (1.0 / (S_LEN - 2));
    const double var2 = (s2q - sd2 * sd2 * (1.0 / (S_LEN - 2))) * (1.0 / (S_LEN - 3));

    float* o = out + (size_t)row * 15;
    o[0]  = (float)mean;
    o[1]  = tmax;
    o[2]  = tmin;
    o[3]  = tmax - tmin;
    o[4]  = (float)var;
    o[5]  = (float)rms;
    o[6]  = (float)skew;
    o[7]  = (float)kurt;
    o[8]  = (float)shape;
    o[9]  = (float)impulse;
    o[10] = outt;
    o[11] = zct * (1.0f / (2.0f * S_LEN));
    o[12] = (float)var;
    o[13] = (float)sqrt(var1 / var);
    o[14] = (float)sqrt(var2 / var1);
}

extern "C" void kernel_launch(void* const* d_in, const int* in_sizes, int n_in,
                              void* d_out, int out_size, void* d_ws, size_t ws_size,
                              hipStream_t stream) {
    (void)in_sizes; (void)n_in; (void)ws_size; (void)out_size;
    const float* in = (const float*)d_in[0];
    float* out = (float*)d_out;
    float* ws  = (float*)d_ws;
    health_pass1<<<8192, 256, 0, stream>>>(in, ws);
    health_finalize<<<64, 256, 0, stream>>>(ws, out);
}

// Round 13
// 36.690 us; speedup vs baseline: 1.2333x; 1.1238x over previous
//
#include <hip/hip_runtime.h>
#include <math.h>

// Health_State_Analysis: B=16384 rows, S=2560 fp32 -> 15 stats/row.
// TRUE R5 (measured 36.7us): k1 2 waves/row, coalesced interleave, DPP
// reductions, packed sp/qp + SCALAR sabs/vmax/vmin in pass 1, ALL f32
// reductions deferred to after pass 2, lag-correlation (r1,r2) Hjorth,
// launch_bounds(256,6). k2: 16384 threads, f64 finalization.

typedef float f32x2 __attribute__((ext_vector_type(2)));
typedef float f32x4 __attribute__((ext_vector_type(4)));

constexpr int S_LEN = 2560;
constexpr int NROWS = 16384;

#define DPP_ADD_F32(x, ctrl) do { \
    int t_ = __builtin_amdgcn_update_dpp(0, __float_as_int(x), ctrl, 0xf, 0xf, false); \
    x += __int_as_float(t_); } while (0)
#define DPP_MAX_F32(x, ctrl) do { \
    int t_ = __builtin_amdgcn_update_dpp(__float_as_int(x), __float_as_int(x), ctrl, 0xf, 0xf, false); \
    x = fmaxf(x, __int_as_float(t_)); } while (0)
#define DPP_MIN_F32(x, ctrl) do { \
    int t_ = __builtin_amdgcn_update_dpp(__float_as_int(x), __float_as_int(x), ctrl, 0xf, 0xf, false); \
    x = fminf(x, __int_as_float(t_)); } while (0)

__device__ __forceinline__ float wave_sum_f32(float x) {
    DPP_ADD_F32(x, 0x111); DPP_ADD_F32(x, 0x112); DPP_ADD_F32(x, 0x114);
    DPP_ADD_F32(x, 0x118); DPP_ADD_F32(x, 0x142); DPP_ADD_F32(x, 0x143);
    return x;  // total in lane 63
}
__device__ __forceinline__ float wave_max_f32(float x) {
    DPP_MAX_F32(x, 0x111); DPP_MAX_F32(x, 0x112); DPP_MAX_F32(x, 0x114);
    DPP_MAX_F32(x, 0x118); DPP_MAX_F32(x, 0x142); DPP_MAX_F32(x, 0x143);
    return x;
}
__device__ __forceinline__ float wave_min_f32(float x) {
    DPP_MIN_F32(x, 0x111); DPP_MIN_F32(x, 0x112); DPP_MIN_F32(x, 0x114);
    DPP_MIN_F32(x, 0x118); DPP_MIN_F32(x, 0x142); DPP_MIN_F32(x, 0x143);
    return x;
}
__device__ __forceinline__ double wave_sum_f64(double x) {
#define DPP_ADD_F64(ctrl) do { \
    long long b_ = __double_as_longlong(x); \
    int lo_ = __builtin_amdgcn_update_dpp(0, (int)(b_ & 0xffffffffLL), ctrl, 0xf, 0xf, false); \
    int hi_ = __builtin_amdgcn_update_dpp(0, (int)(b_ >> 32), ctrl, 0xf, 0xf, false); \
    x += __longlong_as_double(((long long)hi_ << 32) | (unsigned int)lo_); } while (0)
    DPP_ADD_F64(0x111); DPP_ADD_F64(0x112); DPP_ADD_F64(0x114);
    DPP_ADD_F64(0x118); DPP_ADD_F64(0x142); DPP_ADD_F64(0x143);
#undef DPP_ADD_F64
    return x;  // total in lane 63
}
__device__ __forceinline__ double readlane_f64(double x, int l) {
    long long b = __double_as_longlong(x);
    int lo = __builtin_amdgcn_readlane((int)(b & 0xffffffffLL), l);
    int hi = __builtin_amdgcn_readlane((int)(b >> 32), l);
    return __longlong_as_double(((long long)hi << 32) | (unsigned int)lo);
}

__global__ __launch_bounds__(256, 6)
void health_pass1(const float* __restrict__ in, float* __restrict__ ws) {
    __shared__ double Lsum[4], Lsq[4];
    __shared__ float  Lnb[2][2];

    const int lane = threadIdx.x & 63;
    const int wid  = threadIdx.x >> 6;   // 0..3
    const int hidx = wid & 1;            // half of row
    const int rsl  = wid >> 1;           // row slot in block
    const int row  = blockIdx.x * 2 + rsl;

    const f32x4* rp = reinterpret_cast<const f32x4*>(in)
                    + (size_t)row * (S_LEN / 4) + hidx * (1280 / 4) + lane;

    // ---- pass 1: coalesced load + raw sums (packed f32 -> f64 per lane) ----
    f32x4 X[5];
#pragma unroll
    for (int k = 0; k < 5; ++k) X[k] = rp[k * 64];

    f32x2 sp = {0.f, 0.f}, qp = {0.f, 0.f};
    float sabs = 0.f, vmax = -INFINITY, vmin = INFINITY;
#pragma unroll
    for (int k = 0; k < 5; ++k) {
        f32x2 lo = __builtin_shufflevector(X[k], X[k], 0, 1);
        f32x2 hi = __builtin_shufflevector(X[k], X[k], 2, 3);
        sp += lo + hi;
        qp = __builtin_elementwise_fma(lo, lo, qp);
        qp = __builtin_elementwise_fma(hi, hi, qp);
        sabs += (fabsf(X[k][0]) + fabsf(X[k][1])) + (fabsf(X[k][2]) + fabsf(X[k][3]));
        vmax = fmaxf(fmaxf(X[k][2], X[k][3]), fmaxf(fmaxf(X[k][0], X[k][1]), vmax));
        vmin = fminf(fminf(X[k][2], X[k][3]), fminf(fminf(X[k][0], X[k][1]), vmin));
    }

    const double sum_l = (double)sp.x + (double)sp.y;
    const double sq_l  = (double)qp.x + (double)qp.y;
    const double sum_u = readlane_f64(wave_sum_f64(sum_l), 63);
    const double sq_u  = readlane_f64(wave_sum_f64(sq_l), 63);

    // exchange sums with partner wave (other half of row)
    if (lane == 0) {
        Lsum[wid] = sum_u;  Lsq[wid] = sq_u;
        if (hidx == 1) { Lnb[rsl][0] = X[0][0]; Lnb[rsl][1] = X[0][1]; }
    }
    __syncthreads();
    const double tsum = Lsum[rsl * 2] + Lsum[rsl * 2 + 1];
    const double tsq  = Lsq[rsl * 2]  + Lsq[rsl * 2 + 1];

    const double mean = tsum * (1.0 / S_LEN);
    const double var  = (tsq - tsum * mean) * (1.0 / (S_LEN - 1));
    const double thr  = 3.0 * sqrt(var);
    const double bhi = mean + thr, blo = mean - thr;
    float bhi_f = (float)bhi;
    if ((double)bhi_f > bhi) bhi_f = __int_as_float(__float_as_int(bhi_f) - 1);  // RD (bhi>0)
    float blo_f = (float)blo;
    if ((double)blo_f < blo) blo_f = __int_as_float(__float_as_int(blo_f) - 1);  // RU (blo<0)

    // half0 tail splices x[1280],x[1281]; half1 tail pairs don't exist -> 0
    // (zero neighbor makes the invalid lag products vanish exactly)
    const float nbv0 = (hidx == 0) ? Lnb[rsl][0] : 0.f;
    const float nbv1 = (hidx == 0) ? Lnb[rsl][1] : 0.f;
    const float mf = (float)mean;
    const f32x2 nmf2 = {-mf, -mf};

    // ---- pass 2: moments (packed), outliers, zcr, lag correlations ----
    f32x2 c3p = {0.f, 0.f}, c4p = {0.f, 0.f};
    float r1 = 0.f, r2 = 0.f;
    int outc = 0, zcc = 0;
    const unsigned long long tail_ok = (hidx == 0) ? ~0ULL : 0x7FFFFFFFFFFFFFFFULL;

#pragma unroll
    for (int k = 0; k < 5; ++k) {
        const float x0 = X[k][0], x1 = X[k][1], x2v = X[k][2], x3 = X[k][3];
        const int kn = (k == 4) ? 0 : (k + 1);
        float v0 = (lane == 0) ? X[kn][0] : x0;
        float v1 = (lane == 0) ? X[kn][1] : x1;
        float n0 = __shfl(v0, (lane + 1) & 63);
        float n1 = __shfl(v1, (lane + 1) & 63);
        if (k == 4 && lane == 63) { n0 = nbv0; n1 = nbv1; }

        f32x2 lo = __builtin_shufflevector(X[k], X[k], 0, 1);
        f32x2 hi = __builtin_shufflevector(X[k], X[k], 2, 3);
        f32x2 cl = lo + nmf2, ch = hi + nmf2;
        f32x2 ql = cl * cl,  qh = ch * ch;
        c3p = __builtin_elementwise_fma(ql, cl, c3p);
        c3p = __builtin_elementwise_fma(qh, ch, c3p);
        c4p = __builtin_elementwise_fma(ql, ql, c4p);
        c4p = __builtin_elementwise_fma(qh, qh, c4p);

        outc += __popcll(__ballot(x0  > bhi_f || x0  < blo_f));
        outc += __popcll(__ballot(x1  > bhi_f || x1  < blo_f));
        outc += __popcll(__ballot(x2v > bhi_f || x2v < blo_f));
        outc += __popcll(__ballot(x3  > bhi_f || x3  < blo_f));

        const unsigned long long m0 = __ballot(x0  < 0.f);
        const unsigned long long m1 = __ballot(x1  < 0.f);
        const unsigned long long m2 = __ballot(x2v < 0.f);
        const unsigned long long m3 = __ballot(x3  < 0.f);
        const unsigned long long mn = __ballot(n0  < 0.f);
        zcc += __popcll(m0 ^ m1) + __popcll(m1 ^ m2) + __popcll(m2 ^ m3);
        zcc += __popcll((m3 ^ mn) & ((k == 4) ? tail_ok : ~0ULL));

        // lag-1 / lag-2 correlations (replace d1/d2 squared-diff streams)
        r1 = fmaf(x0, x1, fmaf(x1, x2v, fmaf(x2v, x3, fmaf(x3, n0, r1))));
        r2 = fmaf(x0, x2v, fmaf(x1, x3, fmaf(x2v, n0, fmaf(x3, n1, r2))));
    }

    float sabs_t = wave_sum_f32(sabs);
    float c3_t   = wave_sum_f32(c3p.x + c3p.y);
    float c4_t   = wave_sum_f32(c4p.x + c4p.y);
    float r1_t   = wave_sum_f32(r1);
    float r2_t   = wave_sum_f32(r2);
    float vmax_t = wave_max_f32(vmax);
    float vmin_t = wave_min_f32(vmin);

    float ep_a, ep_b;   // half0: x[0],x[1];  half1: x[2558],x[2559]
    if (hidx == 0) {
        ep_a = __int_as_float(__builtin_amdgcn_readlane(__float_as_int(X[0][0]), 0));
        ep_b = __int_as_float(__builtin_amdgcn_readlane(__float_as_int(X[0][1]), 0));
    } else {
        ep_a = X[4][2];  ep_b = X[4][3];   // valid on lane 63 (the storing lane)
    }

    if (lane == 63) {
        double2* Wd = reinterpret_cast<double2*>(ws);
        f32x4*   Wf = reinterpret_cast<f32x4*>(ws);
        double2 dsum; dsum.x = sum_u; dsum.y = sq_u;
        Wd[(size_t)hidx * NROWS + row] = dsum;                       // chunks 0,1
        const size_t b = (size_t)(2 + hidx * 3) * NROWS + row;       // chunks 2..7
        Wf[b]             = f32x4{sabs_t, vmax_t, vmin_t, c3_t};
        Wf[b + NROWS]     = f32x4{c4_t, r1_t, r2_t, (float)outc};
        Wf[b + 2 * NROWS] = f32x4{(float)zcc, ep_a, ep_b, 0.f};
    }
}

__global__ __launch_bounds__(256)
void health_finalize(const float* __restrict__ ws, float* __restrict__ out) {
    const int row = blockIdx.x * 256 + threadIdx.x;
    const double2* Wd = reinterpret_cast<const double2*>(ws);
    const f32x4*   Wf = reinterpret_cast<const f32x4*>(ws);

    const double2 s0 = Wd[row], s1 = Wd[NROWS + row];
    const f32x4 a0 = Wf[2 * NROWS + row], a1 = Wf[3 * NROWS + row], a2 = Wf[4 * NROWS + row];
    const f32x4 b0 = Wf[5 * NROWS + row], b1 = Wf[6 * NROWS + row], b2 = Wf[7 * NROWS + row];

    const double tsum = s0.x + s1.x;
    const double tsq  = s0.y + s1.y;
    const double mean = tsum * (1.0 / S_LEN);
    const double var  = (tsq - tsum * mean) * (1.0 / (S_LEN - 1));
    const double stdv = sqrt(var);

    const float tabs = a0[0] + b0[0];
    const float tmax = fmaxf(a0[1], b0[1]);
    const float tmin = fminf(a0[2], b0[2]);
    const float c3t  = a0[3] + b0[3];
    const float c4t  = a1[0] + b1[0];
    const double r1t = (double)a1[1] + (double)b1[1];
    const double r2t = (double)a1[2] + (double)b1[2];
    const float outt = a1[3] + b1[3];
    const float zct  = a2[0] + b2[0];
    const double e0 = (double)a2[1], e1 = (double)a2[2];   // x[0], x[1]
    const double e2 = (double)b2[1], e3 = (double)b2[2];   // x[2558], x[2559]

    const double rms  = sqrt(tsq * (1.0 / S_LEN));
    const double m3   = (double)c3t * (1.0 / S_LEN);
    const double m4   = (double)c4t * (1.0 / S_LEN);
    const double skew = m3 / (var * stdv);
    const double kurt = m4 / (var * var);
    const float  amax = fmaxf(fabsf(tmax), fabsf(tmin));
    const double shape   = rms * (double)S_LEN / (double)tabs;
    const double impulse = (double)amax * (double)S_LEN / (double)tabs;

    // Hjorth via lag-correlation identities (exact over the f32 samples):
    const double Q = tsq;
    const double s1q = 2.0 * Q - 2.0 * r1t - e0 * e0 - e3 * e3;
    const double s2q = 6.0 * Q - 8.0 * r1t + 2.0 * r2t
                     + 4.0 * (e0 * e1 + e2 * e3)
                     - 5.0 * e0 * e0 - e1 * e1 - e2 * e2 - 5.0 * e3 * e3;
    const double sd1 = e3 - e0;
    const double sd2 = (e3 - e2) - (e1 - e0);
    const double var1 = (s1q - sd1 * sd1 * (1.0 / (S_LEN - 1))) * (1.0 / (S_LEN - 2));
    const double var2 = (s2q - sd2 * sd2 * (1.0 / (S_LEN - 2))) * (1.0 / (S_LEN - 3));

    float* o = out + (size_t)row * 15;
    o[0]  = (float)mean;
    o[1]  = tmax;
    o[2]  = tmin;
    o[3]  = tmax - tmin;
    o[4]  = (float)var;
    o[5]  = (float)rms;
    o[6]  = (float)skew;
    o[7]  = (float)kurt;
    o[8]  = (float)shape;
    o[9]  = (float)impulse;
    o[10] = outt;
    o[11] = zct * (1.0f / (2.0f * S_LEN));
    o[12] = (float)var;
    o[13] = (float)sqrt(var1 / var);
    o[14] = (float)sqrt(var2 / var1);
}

extern "C" void kernel_launch(void* const* d_in, const int* in_sizes, int n_in,
                              void* d_out, int out_size, void* d_ws, size_t ws_size,
                              hipStream_t stream) {
    (void)in_sizes; (void)n_in; (void)ws_size; (void)out_size;
    const float* in = (const float*)d_in[0];
    float* out = (float*)d_out;
    float* ws  = (float*)d_ws;
    health_pass1<<<8192, 256, 0, stream>>>(in, ws);
    health_finalize<<<64, 256, 0, stream>>>(ws, out);
}